// Round 17
// baseline (305.796 us; speedup 1.0000x reference)
//
#include <hip/hip_runtime.h>
#include <math.h>

#define HD 128
#define WD 128
#define HW (HD*WD)

typedef __attribute__((ext_vector_type(8))) short s16x8;     // 8 bf16 (4 VGPRs)
typedef __attribute__((ext_vector_type(4))) float f32x4;     // MFMA acc
typedef __attribute__((ext_vector_type(4))) unsigned int u32x4;
typedef __attribute__((ext_vector_type(2))) float f32x2;
typedef f32x2 __attribute__((aligned(4))) f32x2u;
typedef u32x4 __attribute__((aligned(4))) u32x4u;
typedef __attribute__((ext_vector_type(2))) unsigned int u32x2;
typedef u32x2 __attribute__((aligned(4))) u32x2u;

__device__ inline unsigned int pkbf(float a, float b) {
  unsigned int ua = __builtin_bit_cast(unsigned int, a);
  unsigned int ub = __builtin_bit_cast(unsigned int, b);
  ua = (ua + 0x7fffu + ((ua >> 16) & 1u)) >> 16;
  ub = (ub + 0x7fffu + ((ub >> 16) & 1u)) >> 16;
  return ua | (ub << 16);
}
__device__ __forceinline__ float blo(unsigned int u) {
  return __builtin_bit_cast(float, u << 16);
}
__device__ __forceinline__ float bhi(unsigned int u) {
  return __builtin_bit_cast(float, u & 0xffff0000u);
}

// ---------------------------------------------------------------------------
// Kernel 0a: Wcomb[9][128][128] bf16 for the main contraction.
// ---------------------------------------------------------------------------
__global__ __launch_bounds__(256) void k_prepw(
    const float* __restrict__ wr, const float* __restrict__ wi,
    unsigned short* __restrict__ wc) {
  int t = blockIdx.x * 256 + threadIdx.x;
  if (t >= 9 * 128 * 128) return;
  int c = t & 127;
  int r = (t >> 7) & 127;
  int k = t >> 14;
  float v;
  if (r < 64) v = (c < 64) ? wr[(r * 64 + c) * 9 + k] : -wi[(r * 64 + c - 64) * 9 + k];
  else {
    int r2 = r - 64;
    v = (c < 64) ? wi[(r2 * 64 + c) * 9 + k] : -wr[(r2 * 64 + c - 64) * 9 + k];
  }
  unsigned int u = __builtin_bit_cast(unsigned int, v);
  u = (u + 0x7fffu + ((u >> 16) & 1u)) >> 16;
  wc[t] = (unsigned short)u;
}

// ---------------------------------------------------------------------------
// Kernel 0b: W2[9 taps][32 rows][192 chans] bf16 for the off/mag GEMM.
// ---------------------------------------------------------------------------
__global__ __launch_bounds__(256) void k_prepw2(
    const float* __restrict__ w_off, const float* __restrict__ w_mag,
    unsigned short* __restrict__ w2) {
  int t = blockIdx.x * 256 + threadIdx.x;   // 9*32*192 = 55296 exactly
  int c = t % 192;
  int r = (t / 192) % 32;
  int k = t / (192 * 32);
  float v = 0.f;
  if (r < 18 && c < 128) v = w_off[((size_t)r * 128 + c) * 9 + k];
  else if (r >= 18 && r < 27 && c >= 128) v = w_mag[((size_t)(r - 18) * 64 + (c - 128)) * 9 + k];
  unsigned int u = __builtin_bit_cast(unsigned int, v);
  u = (u + 0x7fffu + ((u >> 16) & 1u)) >> 16;
  w2[t] = (unsigned short)u;
}

// ---------------------------------------------------------------------------
// Kernel 0c: coalesced X4 pack (32 groups/batch — proven L2-friendly layout).
// ---------------------------------------------------------------------------
__global__ __launch_bounds__(256) void k_prepx4(
    const float* __restrict__ xr, const float* __restrict__ xi,
    unsigned int* __restrict__ X4) {
  int b = blockIdx.x & 7;
  int idx = (blockIdx.x >> 3) * 256 + threadIdx.x;   // 0..131071
  int pix4 = idx & 4095;
  int grp = idx >> 12;                               // 0..31
  const float* src = (grp < 16) ? (xr + ((size_t)b * 64 + 4 * grp) * HW)
                                : (xi + ((size_t)b * 64 + 4 * (grp - 16)) * HW);
  const float* p = src + pix4 * 4;
  f32x4 c0 = *(const f32x4*)(p);
  f32x4 c1 = *(const f32x4*)(p + HW);
  f32x4 c2 = *(const f32x4*)(p + 2 * HW);
  f32x4 c3 = *(const f32x4*)(p + 3 * HW);
  u32x4 o0, o1;
#pragma unroll
  for (int j = 0; j < 2; ++j) {
    o0[2 * j] = pkbf(c0[j], c1[j]);
    o0[2 * j + 1] = pkbf(c2[j], c3[j]);
    o1[2 * j] = pkbf(c0[j + 2], c1[j + 2]);
    o1[2 * j + 1] = pkbf(c2[j + 2], c3[j + 2]);
  }
  unsigned int* dst = X4 + ((size_t)(b * 32 + grp) * HW + pix4 * 4) * 2;
  *(u32x4*)(dst) = o0;
  *(u32x4*)(dst + 4) = o1;
}

// ---------------------------------------------------------------------------
// helpers
// ---------------------------------------------------------------------------
__device__ __forceinline__ void tap_weights(
    int h, int w, int k, float dy, float dx, float m,
    float& W00, float& W01, float& W10, float& W11, int& o0, int& o1) {
  float py = (float)(h - 1 + k / 3) + dy;
  float px = (float)(w - 1 + k % 3) + dx;
  float y0f = floorf(py), x0f = floorf(px);
  float wy = py - y0f, wx = px - x0f;
  int y0 = (int)y0f, x0 = (int)x0f;

  int xl = x0 < 0 ? 0 : (x0 > WD - 2 ? WD - 2 : x0);
  float wl, wr;
  if (x0 < 0) { wl = (x0 == -1) ? wx : 0.f; wr = 0.f; }
  else if (x0 > WD - 2) { wl = 0.f; wr = (x0 == WD - 1) ? (1.f - wx) : 0.f; }
  else { wl = 1.f - wx; wr = wx; }

  int y1 = y0 + 1;
  int yc0 = y0 < 0 ? 0 : (y0 > HD - 1 ? HD - 1 : y0);
  int yc1 = y1 < 0 ? 0 : (y1 > HD - 1 ? HD - 1 : y1);
  float cy0 = ((unsigned)y0 < (unsigned)HD) ? (1.f - wy) * m : 0.f;
  float cy1 = ((unsigned)y1 < (unsigned)HD) ? wy * m : 0.f;

  W00 = cy0 * wl; W01 = cy0 * wr;
  W10 = cy1 * wl; W11 = cy1 * wr;
  o0 = yc0 * WD + xl;
  o1 = yc1 * WD + xl;
}

// gather 32 chans (4 slabs of 8) of one tap into swizzled LDS rows
__device__ __forceinline__ void gather_tap4(
    const unsigned int* xq, char* sbase, int swz, int cbase2,
    float W00, float W01, float W10, float W11, int o0, int o1) {
#pragma unroll
  for (int q = 0; q < 4; ++q) {
    const unsigned int* pg0 = xq + (size_t)(q * 2) * (2 * HW);
    const unsigned int* pg1 = pg0 + 2 * HW;
    u32x4 A0 = *(const u32x4u*)(pg0 + 2 * o0);
    u32x4 B0 = *(const u32x4u*)(pg0 + 2 * o1);
    u32x4 A1 = *(const u32x4u*)(pg1 + 2 * o0);
    u32x4 B1 = *(const u32x4u*)(pg1 + 2 * o1);
    float c0 = W00 * blo(A0[0]) + W01 * blo(A0[2]) + W10 * blo(B0[0]) + W11 * blo(B0[2]);
    float c1 = W00 * bhi(A0[0]) + W01 * bhi(A0[2]) + W10 * bhi(B0[0]) + W11 * bhi(B0[2]);
    float c2 = W00 * blo(A0[1]) + W01 * blo(A0[3]) + W10 * blo(B0[1]) + W11 * blo(B0[3]);
    float c3 = W00 * bhi(A0[1]) + W01 * bhi(A0[3]) + W10 * bhi(B0[1]) + W11 * bhi(B0[3]);
    float c4 = W00 * blo(A1[0]) + W01 * blo(A1[2]) + W10 * blo(B1[0]) + W11 * blo(B1[2]);
    float c5 = W00 * bhi(A1[0]) + W01 * bhi(A1[2]) + W10 * bhi(B1[0]) + W11 * bhi(B1[2]);
    float c6 = W00 * blo(A1[1]) + W01 * blo(A1[3]) + W10 * blo(B1[1]) + W11 * blo(B1[3]);
    float c7 = W00 * bhi(A1[1]) + W01 * bhi(A1[3]) + W10 * bhi(B1[1]) + W11 * bhi(B1[3]);
    u32x4 wv;
    wv[0] = pkbf(c0, c1);
    wv[1] = pkbf(c2, c3);
    wv[2] = pkbf(c4, c5);
    wv[3] = pkbf(c6, c7);
    *(u32x4*)(sbase + ((cbase2 + q * 16) ^ swz)) = wv;
  }
}

__device__ __forceinline__ void mfma_tap(
    const unsigned short* Wc, int k, const char* stap,
    int g, int l15, int hi8, int xo, f32x4* accR, f32x4* accI) {
  const unsigned short* wa = Wc + (size_t)k * 16384 + (g * 16 + l15) * 128 + hi8;
  s16x8 aR[4], aI[4];
#pragma unroll
  for (int s = 0; s < 4; ++s) {
    aR[s] = *(const s16x8*)(wa + s * 32);
    aI[s] = *(const s16x8*)(wa + 64 * 128 + s * 32);
  }
  __builtin_amdgcn_s_setprio(1);
#pragma unroll
  for (int t = 0; t < 4; ++t) {
    const char* brow = stap + (t * 16 + l15) * 256;
#pragma unroll
    for (int s = 0; s < 4; ++s) {
      s16x8 bf = *(const s16x8*)(brow + ((s * 64 + (hi8 << 1)) ^ xo));
      accR[t] = __builtin_amdgcn_mfma_f32_16x16x32_bf16(aR[s], bf, accR[t], 0, 0, 0);
      accI[t] = __builtin_amdgcn_mfma_f32_16x16x32_bf16(aI[s], bf, accI[t], 0, 0, 0);
    }
  }
  __builtin_amdgcn_s_setprio(0);
}

// load one 4-chan group (u32x2) for 192-space pair-index g2 (mag on the fly)
__device__ __forceinline__ u32x2 stage_pair(
    const unsigned int* __restrict__ X4, int b, int g2, int pix) {
  if (g2 < 32) {
    return *(const u32x2u*)&X4[((size_t)(b * 32 + g2) * HW + pix) * 2];
  }
  int gm = g2 - 32;
  u32x2 A = *(const u32x2u*)&X4[((size_t)(b * 32 + gm) * HW + pix) * 2];
  u32x2 B = *(const u32x2u*)&X4[((size_t)(b * 32 + 16 + gm) * HW + pix) * 2];
  u32x2 r;
  r.x = pkbf(sqrtf(blo(A.x) * blo(A.x) + blo(B.x) * blo(B.x)),
             sqrtf(bhi(A.x) * bhi(A.x) + bhi(B.x) * bhi(B.x)));
  r.y = pkbf(sqrtf(blo(A.y) * blo(A.y) + blo(B.y) * blo(B.y)),
             sqrtf(bhi(A.y) * bhi(A.y) + bhi(B.y) * bhi(B.y)));
  return r;
}

// ---------------------------------------------------------------------------
// DE-FUSED phase A: offset+mag conv GEMM from X4, results to global ws.
// (verbatim fused-phase-A body; only the epilogue changed.)
// ---------------------------------------------------------------------------
__global__ __launch_bounds__(256) void k_offmag_x4(
    const unsigned int* __restrict__ X4,
    const unsigned short* __restrict__ W2,
    float* __restrict__ off_o, float* __restrict__ mag_o) {
  __shared__ __align__(16) char LB[33792];

  int blk = blockIdx.x;
  int b = blk & 7;                 // XCD-affine
  int rest = blk >> 3;
  int wt = rest & 1;
  int h = rest >> 1;
  int w0 = wt * 64;

  int tid = threadIdx.x;
  int lane = tid & 63;
  int g = tid >> 6;
  int l15 = lane & 15;
  int hi8 = (lane >> 4) * 8;

  int sub = tid & 3;
  int colm = tid >> 2;
  int jm = colm + 1;
  int wm = w0 + colm;

  f32x4 acc[2];
  acc[0] = (f32x4)(0.f);
  acc[1] = (f32x4)(0.f);

#pragma unroll 1
  for (int ty = 0; ty < 3; ++ty) {
    int y = h + ty - 1;
    if ((unsigned)y >= (unsigned)HD) continue;
    __syncthreads();
    int rb = y * WD;

#pragma unroll
    for (int i = 0; i < 12; ++i) {
      int g2 = sub + i * 4;                        // 0..47
      u32x2 pk2 = stage_pair(X4, b, g2, rb + wm);
      *(u32x2*)(LB + jm * 512 + ((8 * g2) ^ ((jm & 7) << 4))) = pk2;
    }
    if (tid < 96) {
      int j = (tid < 48) ? 0 : 65;
      int g2 = (tid < 48) ? tid : tid - 48;
      int wg = (j == 0) ? (w0 - 1) : (w0 + 64);
      u32x2 pk2;
      pk2.x = 0u; pk2.y = 0u;
      if ((unsigned)wg < (unsigned)WD) pk2 = stage_pair(X4, b, g2, rb + wg);
      *(u32x2*)(LB + j * 512 + ((8 * g2) ^ ((j & 7) << 4))) = pk2;
    }
    __syncthreads();

#pragma unroll
    for (int tx = 0; tx < 3; ++tx) {
      const unsigned short* wtap = W2 + (size_t)(ty * 3 + tx) * 32 * 192;
      int j = g * 16 + l15 + tx;
      const char* bcol = LB + j * 512;
      int xo2 = (j & 7) << 4;
#pragma unroll
      for (int s = 0; s < 6; ++s) {
        s16x8 bf = *(const s16x8*)(bcol + ((s * 64 + hi8 * 2) ^ xo2));
#pragma unroll
        for (int mt = 0; mt < 2; ++mt) {
          s16x8 af = *(const s16x8*)(wtap + (mt * 16 + l15) * 192 + s * 32 + hi8);
          acc[mt] = __builtin_amdgcn_mfma_f32_16x16x32_bf16(af, bf, acc[mt], 0, 0, 0);
        }
      }
    }
  }

  int p = h * WD + w0 + g * 16 + l15;
#pragma unroll
  for (int mt = 0; mt < 2; ++mt) {
#pragma unroll
    for (int r = 0; r < 4; ++r) {
      int row = mt * 16 + (lane >> 4) * 4 + r;
      float v = acc[mt][r];
      if (row < 18) off_o[((size_t)(b * 18 + row)) * HW + p] = v;
      else if (row < 27) mag_o[((size_t)(b * 9 + row - 18)) * HW + p] = 1.f / (1.f + expf(-v));
    }
  }
}

// ---------------------------------------------------------------------------
// DE-FUSED phase B: deformable sampling + complex contraction (round-11
// proven ~87µs kernel: X4 gathers, off/mag from global).
// ---------------------------------------------------------------------------
__global__ __launch_bounds__(256, 4) void k_main_x4(
    const unsigned int* __restrict__ X4,
    const float* __restrict__ off_i, const float* __restrict__ mag_i,
    const unsigned short* __restrict__ Wc,
    const float* __restrict__ b_real, const float* __restrict__ b_imag,
    float* __restrict__ out) {
  __shared__ __align__(16) char LB[2 * 16384];   // 32 KB

  int blk = blockIdx.x;
  int b = blk & 7;                 // XCD-affine
  int rest = blk >> 3;
  int wt = rest & 1;
  int h = rest >> 1;
  int w0 = wt * 64;

  int tid = threadIdx.x;
  int lane = tid & 63;
  int g = tid >> 6;
  int w = w0 + lane;
  int l15 = lane & 15;
  int hi8 = (lane >> 4) * 8;
  int xo = l15 << 4;
  int swz = (lane & 15) << 4;
  int cbase = g * 32;
  const unsigned int* xq = X4 + (size_t)(b * 32 + g * 8) * (2 * HW);
  int ppos = h * WD + w;
  char* sb0 = LB + lane * 256;
  char* sb1 = LB + 16384 + lane * 256;

  f32x4 accR[4], accI[4];
#pragma unroll
  for (int t = 0; t < 4; ++t) {
    accR[t] = (f32x4)(0.f);
    accI[t] = (f32x4)(0.f);
  }

#pragma unroll 1
  for (int ph = 0; ph < 5; ++ph) {
    int kA = ph * 2;
    int kB = kA + 1;
    bool two = (ph < 4);

    float dyA = off_i[((size_t)(b * 18 + 2 * kA)) * HW + ppos];
    float dxA = off_i[((size_t)(b * 18 + 2 * kA + 1)) * HW + ppos];
    float mA  = mag_i[((size_t)(b * 9 + kA)) * HW + ppos];
    float dyB = 0.f, dxB = 0.f, mB = 0.f;
    if (two) {
      dyB = off_i[((size_t)(b * 18 + 2 * kB)) * HW + ppos];
      dxB = off_i[((size_t)(b * 18 + 2 * kB + 1)) * HW + ppos];
      mB  = mag_i[((size_t)(b * 9 + kB)) * HW + ppos];
    }

    __syncthreads();   // prev MFMA phase done reading tap buffers

    {
      float W00, W01, W10, W11; int o0, o1;
      tap_weights(h, w, kA, dyA, dxA, mA, W00, W01, W10, W11, o0, o1);
      gather_tap4(xq, sb0, swz, cbase * 2, W00, W01, W10, W11, o0, o1);
    }
    if (two) {
      float W00, W01, W10, W11; int o0, o1;
      tap_weights(h, w, kB, dyB, dxB, mB, W00, W01, W10, W11, o0, o1);
      gather_tap4(xq, sb1, swz, cbase * 2, W00, W01, W10, W11, o0, o1);
    }
    __syncthreads();

    mfma_tap(Wc, kA, LB, g, l15, hi8, xo, accR, accI);
    if (two)
      mfma_tap(Wc, kB, LB + 16384, g, l15, hi8, xo, accR, accI);
  }

  // epilogue: bias + coalesced nontemporal f32x2 stores
  f32x2* outp = (f32x2*)out;
#pragma unroll
  for (int r = 0; r < 4; ++r) {
    int o = g * 16 + (lane >> 4) * 4 + r;
    float br = b_real[o] - b_imag[o];
#pragma unroll
    for (int t = 0; t < 4; ++t) {
      int pe = h * WD + w0 + t * 16 + l15;
      f32x2 v;
      v.x = accR[t][r] + br;
      v.y = accI[t][r] - br;
      __builtin_nontemporal_store(v, &outp[((size_t)(b * 64 + o)) * HW + pe]);
    }
  }
}

// ---------------------------------------------------------------------------
// Fallback path (ws too small for X4): f32 kernels (round-11 proven).
// ---------------------------------------------------------------------------
__global__ __launch_bounds__(256) void k_offmag_f32(
    const float* __restrict__ xr, const float* __restrict__ xi,
    const unsigned short* __restrict__ W2,
    float* __restrict__ off_o, float* __restrict__ mag_o) {
  __shared__ unsigned short S[66 * 256];
  int blk = blockIdx.x;
  int b = blk & 7;
  int rest = blk >> 3;
  int wt = rest & 1;
  int h = rest >> 1;
  int w0 = wt * 64;
  int tid = threadIdx.x;
  int lane = tid & 63;
  int g = tid >> 6;
  int l15 = lane & 15;
  int hi8 = (lane >> 4) * 8;
  const float* xrb = xr + (size_t)b * 64 * HW;
  const float* xib = xi + (size_t)b * 64 * HW;
  int sub = tid & 3;
  int colm = tid >> 2;
  int jm = colm + 1;
  int wm = w0 + colm;
  f32x4 acc[2];
  acc[0] = (f32x4)(0.f);
  acc[1] = (f32x4)(0.f);
#pragma unroll 1
  for (int ty = 0; ty < 3; ++ty) {
    int y = h + ty - 1;
    if ((unsigned)y >= (unsigned)HD) continue;
    __syncthreads();
    int rb = y * WD;
#pragma unroll
    for (int i = 0; i < 24; ++i) {
      int s = sub + i * 4;
      float v0, v1;
      if (s < 32) {
        const float* p = xrb + (size_t)(2 * s) * HW + rb + wm;
        v0 = p[0]; v1 = p[HW];
      } else if (s < 64) {
        const float* p = xib + (size_t)(2 * s - 64) * HW + rb + wm;
        v0 = p[0]; v1 = p[HW];
      } else {
        int c = 2 * s - 128;
        const float* pr = xrb + (size_t)c * HW + rb + wm;
        const float* pi = xib + (size_t)c * HW + rb + wm;
        float a0 = pr[0], a1 = pr[HW];
        float b0 = pi[0], b1 = pi[HW];
        v0 = sqrtf(a0 * a0 + b0 * b0);
        v1 = sqrtf(a1 * a1 + b1 * b1);
      }
      *(unsigned int*)((char*)S + jm * 512 + ((4 * s) ^ ((jm & 7) << 4))) = pkbf(v0, v1);
    }
    if (tid < 192) {
      int j = (tid < 96) ? 0 : 65;
      int s = (tid < 96) ? tid : tid - 96;
      int wg = (j == 0) ? (w0 - 1) : (w0 + 64);
      float v0 = 0.f, v1 = 0.f;
      if ((unsigned)wg < (unsigned)WD) {
        if (s < 32) {
          const float* p = xrb + (size_t)(2 * s) * HW + rb + wg;
          v0 = p[0]; v1 = p[HW];
        } else if (s < 64) {
          const float* p = xib + (size_t)(2 * s - 64) * HW + rb + wg;
          v0 = p[0]; v1 = p[HW];
        } else {
          int c = 2 * s - 128;
          const float* pr = xrb + (size_t)c * HW + rb + wg;
          const float* pi = xib + (size_t)c * HW + rb + wg;
          float a0 = pr[0], a1 = pr[HW];
          float b0 = pi[0], b1 = pi[HW];
          v0 = sqrtf(a0 * a0 + b0 * b0);
          v1 = sqrtf(a1 * a1 + b1 * b1);
        }
      }
      *(unsigned int*)((char*)S + j * 512 + ((4 * s) ^ ((j & 7) << 4))) = pkbf(v0, v1);
    }
    __syncthreads();
#pragma unroll
    for (int tx = 0; tx < 3; ++tx) {
      const unsigned short* wtap = W2 + (size_t)(ty * 3 + tx) * 32 * 192;
      int j = g * 16 + l15 + tx;
      const char* bcol = (const char*)S + j * 512;
      int xo = (j & 7) << 4;
#pragma unroll
      for (int s = 0; s < 6; ++s) {
        s16x8 bf = *(const s16x8*)(bcol + ((s * 64 + hi8 * 2) ^ xo));
#pragma unroll
        for (int mt = 0; mt < 2; ++mt) {
          s16x8 af = *(const s16x8*)(wtap + (mt * 16 + l15) * 192 + s * 32 + hi8);
          acc[mt] = __builtin_amdgcn_mfma_f32_16x16x32_bf16(af, bf, acc[mt], 0, 0, 0);
        }
      }
    }
  }
  int p = h * WD + w0 + g * 16 + l15;
#pragma unroll
  for (int mt = 0; mt < 2; ++mt) {
#pragma unroll
    for (int r = 0; r < 4; ++r) {
      int row = mt * 16 + (lane >> 4) * 4 + r;
      float v = acc[mt][r];
      if (row < 18) off_o[((size_t)(b * 18 + row)) * HW + p] = v;
      else if (row < 27) mag_o[((size_t)(b * 9 + row - 18)) * HW + p] = 1.f / (1.f + expf(-v));
    }
  }
}

__device__ __forceinline__ void gather_tap_f32(
    const float* xbase, char* sbase, int swz, int cbase2,
    float W00, float W01, float W10, float W11, int o0, int o1) {
#pragma unroll
  for (int q = 0; q < 4; ++q) {
    u32x4 wv;
#pragma unroll
    for (int j2 = 0; j2 < 4; ++j2) {
      const float* p0 = xbase + (size_t)(q * 8 + j2 * 2) * HW;
      const float* p1 = p0 + HW;
      f32x2u a0 = *(const f32x2u*)(p0 + o0);
      f32x2u b0 = *(const f32x2u*)(p0 + o1);
      f32x2u a1 = *(const f32x2u*)(p1 + o0);
      f32x2u b1 = *(const f32x2u*)(p1 + o1);
      float v0 = W00 * a0.x + W01 * a0.y + W10 * b0.x + W11 * b0.y;
      float v1 = W00 * a1.x + W01 * a1.y + W10 * b1.x + W11 * b1.y;
      wv[j2] = pkbf(v0, v1);
    }
    *(u32x4*)(sbase + ((cbase2 + q * 16) ^ swz)) = wv;
  }
}

__global__ __launch_bounds__(256, 4) void k_main_f32(
    const float* __restrict__ xr, const float* __restrict__ xi,
    const float* __restrict__ off_i, const float* __restrict__ mag_i,
    const unsigned short* __restrict__ Wc,
    const float* __restrict__ b_real, const float* __restrict__ b_imag,
    float* __restrict__ out) {
  __shared__ unsigned short S[2 * 64 * 128];
  int blk = blockIdx.x;
  int b = blk & 7;
  int rest = blk >> 3;
  int wt = rest & 1;
  int h = rest >> 1;
  int w0 = wt * 64;
  int tid = threadIdx.x;
  int lane = tid & 63;
  int g = tid >> 6;
  int w = w0 + lane;
  int l15 = lane & 15;
  int hi8 = (lane >> 4) * 8;
  int xo = l15 << 4;
  int swz = (lane & 15) << 4;
  const float* xrb = xr + (size_t)b * 64 * HW;
  const float* xib = xi + (size_t)b * 64 * HW;
  int cbase = g * 32;
  const float* xbase = (g < 2) ? (xrb + (size_t)cbase * HW)
                               : (xib + (size_t)(cbase - 64) * HW);
  int ppos = h * WD + w;
  char* sb0 = (char*)S + lane * 256;
  char* sb1 = (char*)S + 16384 + lane * 256;
  f32x4 accR[4], accI[4];
#pragma unroll
  for (int t = 0; t < 4; ++t) {
    accR[t] = (f32x4)(0.f);
    accI[t] = (f32x4)(0.f);
  }
#pragma unroll 1
  for (int ph = 0; ph < 5; ++ph) {
    int kA = ph * 2;
    int kB = kA + 1;
    bool two = (ph < 4);
    float dyA = off_i[((size_t)(b * 18 + 2 * kA)) * HW + ppos];
    float dxA = off_i[((size_t)(b * 18 + 2 * kA + 1)) * HW + ppos];
    float mA  = mag_i[((size_t)(b * 9 + kA)) * HW + ppos];
    float dyB = 0.f, dxB = 0.f, mB = 0.f;
    if (two) {
      dyB = off_i[((size_t)(b * 18 + 2 * kB)) * HW + ppos];
      dxB = off_i[((size_t)(b * 18 + 2 * kB + 1)) * HW + ppos];
      mB  = mag_i[((size_t)(b * 9 + kB)) * HW + ppos];
    }
    __syncthreads();
    {
      float W00, W01, W10, W11; int o0, o1;
      tap_weights(h, w, kA, dyA, dxA, mA, W00, W01, W10, W11, o0, o1);
      gather_tap_f32(xbase, sb0, swz, cbase * 2, W00, W01, W10, W11, o0, o1);
    }
    if (two) {
      float W00, W01, W10, W11; int o0, o1;
      tap_weights(h, w, kB, dyB, dxB, mB, W00, W01, W10, W11, o0, o1);
      gather_tap_f32(xbase, sb1, swz, cbase * 2, W00, W01, W10, W11, o0, o1);
    }
    __syncthreads();
    mfma_tap(Wc, kA, (const char*)S, g, l15, hi8, xo, accR, accI);
    if (two)
      mfma_tap(Wc, kB, (const char*)S + 16384, g, l15, hi8, xo, accR, accI);
  }
  f32x2* outp = (f32x2*)out;
#pragma unroll
  for (int r = 0; r < 4; ++r) {
    int o = g * 16 + (lane >> 4) * 4 + r;
    float br = b_real[o] - b_imag[o];
#pragma unroll
    for (int t = 0; t < 4; ++t) {
      int pe = h * WD + w0 + t * 16 + l15;
      f32x2 v;
      v.x = accR[t][r] + br;
      v.y = accI[t][r] - br;
      __builtin_nontemporal_store(v, &outp[((size_t)(b * 64 + o)) * HW + pe]);
    }
  }
}

// ---------------------------------------------------------------------------
extern "C" void kernel_launch(void* const* d_in, const int* in_sizes, int n_in,
                              void* d_out, int out_size, void* d_ws, size_t ws_size,
                              hipStream_t stream) {
  const float* xr     = (const float*)d_in[0];
  const float* xi     = (const float*)d_in[1];
  const float* w_off  = (const float*)d_in[2];
  const float* w_mag  = (const float*)d_in[3];
  const float* w_real = (const float*)d_in[4];
  const float* w_imag = (const float*)d_in[5];
  const float* b_real = (const float*)d_in[6];
  const float* b_imag = (const float*)d_in[7];
  float* out = (float*)d_out;

  unsigned short* Wc = (unsigned short*)d_ws;        // 147456 bf16
  unsigned short* W2 = Wc + 147456;                  // 55296 bf16
  float* off_ws = (float*)(W2 + 55296);              // 2359296 f
  float* mag_ws = off_ws + 2359296;                  // 1179648 f
  unsigned int* X4 = (unsigned int*)(mag_ws + 1179648); // 8388608 u32
  const size_t need = ((char*)(X4 + 8388608)) - ((char*)d_ws);
  bool use_x4 = ws_size >= need;

  hipLaunchKernelGGL(k_prepw, dim3(576), dim3(256), 0, stream,
                     w_real, w_imag, Wc);
  hipLaunchKernelGGL(k_prepw2, dim3(216), dim3(256), 0, stream,
                     w_off, w_mag, W2);
  if (use_x4) {
    hipLaunchKernelGGL(k_prepx4, dim3(4096), dim3(256), 0, stream, xr, xi, X4);
    hipLaunchKernelGGL(k_offmag_x4, dim3(2048), dim3(256), 0, stream,
                       X4, W2, off_ws, mag_ws);
    hipLaunchKernelGGL(k_main_x4, dim3(2048), dim3(256), 0, stream,
                       X4, off_ws, mag_ws, Wc, b_real, b_imag, out);
  } else {
    hipLaunchKernelGGL(k_offmag_f32, dim3(2048), dim3(256), 0, stream,
                       xr, xi, W2, off_ws, mag_ws);
    hipLaunchKernelGGL(k_main_f32, dim3(2048), dim3(256), 0, stream,
                       xr, xi, off_ws, mag_ws, Wc, b_real, b_imag, out);
  }
}

// Round 18
// 232.570 us; speedup vs baseline: 1.3149x; 1.3149x over previous
//
#include <hip/hip_runtime.h>
#include <math.h>

#define HD 128
#define WD 128
#define HW (HD*WD)

typedef __attribute__((ext_vector_type(8))) short s16x8;     // 8 bf16 (4 VGPRs)
typedef __attribute__((ext_vector_type(4))) float f32x4;     // MFMA acc
typedef __attribute__((ext_vector_type(4))) unsigned int u32x4;
typedef __attribute__((ext_vector_type(2))) float f32x2;
typedef f32x2 __attribute__((aligned(4))) f32x2u;
typedef u32x4 __attribute__((aligned(4))) u32x4u;
typedef __attribute__((ext_vector_type(2))) unsigned int u32x2;
typedef u32x2 __attribute__((aligned(4))) u32x2u;

__device__ inline unsigned int pkbf(float a, float b) {
  unsigned int ua = __builtin_bit_cast(unsigned int, a);
  unsigned int ub = __builtin_bit_cast(unsigned int, b);
  ua = (ua + 0x7fffu + ((ua >> 16) & 1u)) >> 16;
  ub = (ub + 0x7fffu + ((ub >> 16) & 1u)) >> 16;
  return ua | (ub << 16);
}
__device__ __forceinline__ float blo(unsigned int u) {
  return __builtin_bit_cast(float, u << 16);
}
__device__ __forceinline__ float bhi(unsigned int u) {
  return __builtin_bit_cast(float, u & 0xffff0000u);
}

// ---------------------------------------------------------------------------
// Kernel 0a: Wcomb[9][128][128] bf16 for the main contraction.
// ---------------------------------------------------------------------------
__global__ __launch_bounds__(256) void k_prepw(
    const float* __restrict__ wr, const float* __restrict__ wi,
    unsigned short* __restrict__ wc) {
  int t = blockIdx.x * 256 + threadIdx.x;
  if (t >= 9 * 128 * 128) return;
  int c = t & 127;
  int r = (t >> 7) & 127;
  int k = t >> 14;
  float v;
  if (r < 64) v = (c < 64) ? wr[(r * 64 + c) * 9 + k] : -wi[(r * 64 + c - 64) * 9 + k];
  else {
    int r2 = r - 64;
    v = (c < 64) ? wi[(r2 * 64 + c) * 9 + k] : -wr[(r2 * 64 + c - 64) * 9 + k];
  }
  unsigned int u = __builtin_bit_cast(unsigned int, v);
  u = (u + 0x7fffu + ((u >> 16) & 1u)) >> 16;
  wc[t] = (unsigned short)u;
}

// ---------------------------------------------------------------------------
// Kernel 0b: W2[9 taps][32 rows][192 chans] bf16 for the off/mag GEMM.
// ---------------------------------------------------------------------------
__global__ __launch_bounds__(256) void k_prepw2(
    const float* __restrict__ w_off, const float* __restrict__ w_mag,
    unsigned short* __restrict__ w2) {
  int t = blockIdx.x * 256 + threadIdx.x;   // 9*32*192 = 55296 exactly
  int c = t % 192;
  int r = (t / 192) % 32;
  int k = t / (192 * 32);
  float v = 0.f;
  if (r < 18 && c < 128) v = w_off[((size_t)r * 128 + c) * 9 + k];
  else if (r >= 18 && r < 27 && c >= 128) v = w_mag[((size_t)(r - 18) * 64 + (c - 128)) * 9 + k];
  unsigned int u = __builtin_bit_cast(unsigned int, v);
  u = (u + 0x7fffu + ((u >> 16) & 1u)) >> 16;
  w2[t] = (unsigned short)u;
}

// ---------------------------------------------------------------------------
// Kernel 0c: coalesced X4 pack (32 groups/batch — proven L2-friendly layout).
// ---------------------------------------------------------------------------
__global__ __launch_bounds__(256) void k_prepx4(
    const float* __restrict__ xr, const float* __restrict__ xi,
    unsigned int* __restrict__ X4) {
  int b = blockIdx.x & 7;
  int idx = (blockIdx.x >> 3) * 256 + threadIdx.x;   // 0..131071
  int pix4 = idx & 4095;
  int grp = idx >> 12;                               // 0..31
  const float* src = (grp < 16) ? (xr + ((size_t)b * 64 + 4 * grp) * HW)
                                : (xi + ((size_t)b * 64 + 4 * (grp - 16)) * HW);
  const float* p = src + pix4 * 4;
  f32x4 c0 = *(const f32x4*)(p);
  f32x4 c1 = *(const f32x4*)(p + HW);
  f32x4 c2 = *(const f32x4*)(p + 2 * HW);
  f32x4 c3 = *(const f32x4*)(p + 3 * HW);
  u32x4 o0, o1;
#pragma unroll
  for (int j = 0; j < 2; ++j) {
    o0[2 * j] = pkbf(c0[j], c1[j]);
    o0[2 * j + 1] = pkbf(c2[j], c3[j]);
    o1[2 * j] = pkbf(c0[j + 2], c1[j + 2]);
    o1[2 * j + 1] = pkbf(c2[j + 2], c3[j + 2]);
  }
  unsigned int* dst = X4 + ((size_t)(b * 32 + grp) * HW + pix4 * 4) * 2;
  *(u32x4*)(dst) = o0;
  *(u32x4*)(dst + 4) = o1;
}

// ---------------------------------------------------------------------------
// helpers
// ---------------------------------------------------------------------------
__device__ __forceinline__ void tap_weights(
    int h, int w, int k, float dy, float dx, float m,
    float& W00, float& W01, float& W10, float& W11, int& o0, int& o1) {
  float py = (float)(h - 1 + k / 3) + dy;
  float px = (float)(w - 1 + k % 3) + dx;
  float y0f = floorf(py), x0f = floorf(px);
  float wy = py - y0f, wx = px - x0f;
  int y0 = (int)y0f, x0 = (int)x0f;

  int xl = x0 < 0 ? 0 : (x0 > WD - 2 ? WD - 2 : x0);
  float wl, wr;
  if (x0 < 0) { wl = (x0 == -1) ? wx : 0.f; wr = 0.f; }
  else if (x0 > WD - 2) { wl = 0.f; wr = (x0 == WD - 1) ? (1.f - wx) : 0.f; }
  else { wl = 1.f - wx; wr = wx; }

  int y1 = y0 + 1;
  int yc0 = y0 < 0 ? 0 : (y0 > HD - 1 ? HD - 1 : y0);
  int yc1 = y1 < 0 ? 0 : (y1 > HD - 1 ? HD - 1 : y1);
  float cy0 = ((unsigned)y0 < (unsigned)HD) ? (1.f - wy) * m : 0.f;
  float cy1 = ((unsigned)y1 < (unsigned)HD) ? wy * m : 0.f;

  W00 = cy0 * wl; W01 = cy0 * wr;
  W10 = cy1 * wl; W11 = cy1 * wr;
  o0 = yc0 * WD + xl;
  o1 = yc1 * WD + xl;
}

// gather 32 chans (4 slabs of 8) of one tap into swizzled LDS rows
__device__ __forceinline__ void gather_tap4(
    const unsigned int* xq, char* sbase, int swz, int cbase2,
    float W00, float W01, float W10, float W11, int o0, int o1) {
#pragma unroll
  for (int q = 0; q < 4; ++q) {
    const unsigned int* pg0 = xq + (size_t)(q * 2) * (2 * HW);
    const unsigned int* pg1 = pg0 + 2 * HW;
    u32x4 A0 = *(const u32x4u*)(pg0 + 2 * o0);
    u32x4 B0 = *(const u32x4u*)(pg0 + 2 * o1);
    u32x4 A1 = *(const u32x4u*)(pg1 + 2 * o0);
    u32x4 B1 = *(const u32x4u*)(pg1 + 2 * o1);
    float c0 = W00 * blo(A0[0]) + W01 * blo(A0[2]) + W10 * blo(B0[0]) + W11 * blo(B0[2]);
    float c1 = W00 * bhi(A0[0]) + W01 * bhi(A0[2]) + W10 * bhi(B0[0]) + W11 * bhi(B0[2]);
    float c2 = W00 * blo(A0[1]) + W01 * blo(A0[3]) + W10 * blo(B0[1]) + W11 * blo(B0[3]);
    float c3 = W00 * bhi(A0[1]) + W01 * bhi(A0[3]) + W10 * bhi(B0[1]) + W11 * bhi(B0[3]);
    float c4 = W00 * blo(A1[0]) + W01 * blo(A1[2]) + W10 * blo(B1[0]) + W11 * blo(B1[2]);
    float c5 = W00 * bhi(A1[0]) + W01 * bhi(A1[2]) + W10 * bhi(B1[0]) + W11 * bhi(B1[2]);
    float c6 = W00 * blo(A1[1]) + W01 * blo(A1[3]) + W10 * blo(B1[1]) + W11 * blo(B1[3]);
    float c7 = W00 * bhi(A1[1]) + W01 * bhi(A1[3]) + W10 * bhi(B1[1]) + W11 * bhi(B1[3]);
    u32x4 wv;
    wv[0] = pkbf(c0, c1);
    wv[1] = pkbf(c2, c3);
    wv[2] = pkbf(c4, c5);
    wv[3] = pkbf(c6, c7);
    *(u32x4*)(sbase + ((cbase2 + q * 16) ^ swz)) = wv;
  }
}

__device__ __forceinline__ void mfma_tap(
    const unsigned short* Wc, int k, const char* stap,
    int g, int l15, int hi8, int xo, f32x4* accR, f32x4* accI) {
  const unsigned short* wa = Wc + (size_t)k * 16384 + (g * 16 + l15) * 128 + hi8;
  s16x8 aR[4], aI[4];
#pragma unroll
  for (int s = 0; s < 4; ++s) {
    aR[s] = *(const s16x8*)(wa + s * 32);
    aI[s] = *(const s16x8*)(wa + 64 * 128 + s * 32);
  }
  __builtin_amdgcn_s_setprio(1);
#pragma unroll
  for (int t = 0; t < 4; ++t) {
    const char* brow = stap + (t * 16 + l15) * 256;
#pragma unroll
    for (int s = 0; s < 4; ++s) {
      s16x8 bf = *(const s16x8*)(brow + ((s * 64 + (hi8 << 1)) ^ xo));
      accR[t] = __builtin_amdgcn_mfma_f32_16x16x32_bf16(aR[s], bf, accR[t], 0, 0, 0);
      accI[t] = __builtin_amdgcn_mfma_f32_16x16x32_bf16(aI[s], bf, accI[t], 0, 0, 0);
    }
  }
  __builtin_amdgcn_s_setprio(0);
}

// load one 4-chan group (u32x2) for 192-space pair-index g2 (mag on the fly)
__device__ __forceinline__ u32x2 stage_pair(
    const unsigned int* __restrict__ X4, int b, int g2, int pix) {
  if (g2 < 32) {
    return *(const u32x2u*)&X4[((size_t)(b * 32 + g2) * HW + pix) * 2];
  }
  int gm = g2 - 32;
  u32x2 A = *(const u32x2u*)&X4[((size_t)(b * 32 + gm) * HW + pix) * 2];
  u32x2 B = *(const u32x2u*)&X4[((size_t)(b * 32 + 16 + gm) * HW + pix) * 2];
  u32x2 r;
  r.x = pkbf(sqrtf(blo(A.x) * blo(A.x) + blo(B.x) * blo(B.x)),
             sqrtf(bhi(A.x) * bhi(A.x) + bhi(B.x) * bhi(B.x)));
  r.y = pkbf(sqrtf(blo(A.y) * blo(A.y) + blo(B.y) * blo(B.y)),
             sqrtf(bhi(A.y) * bhi(A.y) + bhi(B.y) * bhi(B.y)));
  return r;
}

// ---------------------------------------------------------------------------
// Phase A v2: FULL-ROW blocks (128 pixels, 1024 blocks).  Each wave owns 2
// n-tiles, so every batched af fragment feeds 2 MFMAs; each input row staged
// once; halos are pure zero-pad.  LDS [48 grp][130 col] u32x2, stride 1040B.
// ---------------------------------------------------------------------------
__global__ __launch_bounds__(256) void k_offmag_x4(
    const unsigned int* __restrict__ X4,
    const unsigned short* __restrict__ W2,
    float* __restrict__ off_o, float* __restrict__ mag_o) {
  __shared__ __align__(16) char LB[48 * 130 * 8];   // 49920 B

  int blk = blockIdx.x;            // 0..1023
  int b = blk & 7;                 // XCD-affine
  int h = blk >> 3;                // 0..127

  int tid = threadIdx.x;
  int lane = tid & 63;
  int g = tid >> 6;
  int l15 = lane & 15;
  int hi8 = (lane >> 4) * 8;

  int sub = tid & 1;               // 24-group half
  int colx = tid >> 1;             // input w 0..127
  int jm = colx + 1;               // LDS col

  f32x4 acc00 = (f32x4)(0.f), acc01 = (f32x4)(0.f);
  f32x4 acc10 = (f32x4)(0.f), acc11 = (f32x4)(0.f);   // [mt][nt]

#pragma unroll 1
  for (int ty = 0; ty < 3; ++ty) {
    int y = h + ty - 1;
    if ((unsigned)y >= (unsigned)HD) continue;
    __syncthreads();
    int rb = y * WD;

    // stage 24 interleaved groups of this thread's input column
#pragma unroll
    for (int i = 0; i < 24; ++i) {
      int g2 = 2 * i + sub;        // 0..47
      u32x2 pk2 = stage_pair(X4, b, g2, rb + colx);
      *(u32x2*)(LB + g2 * 1040 + jm * 8) = pk2;
    }
    // zero halos (input w = -1 and 128)
    if (tid < 96) {
      int j = (tid < 48) ? 0 : 129;
      int g2 = (tid < 48) ? tid : tid - 48;
      u32x2 z;
      z.x = 0u; z.y = 0u;
      *(u32x2*)(LB + g2 * 1040 + j * 8) = z;
    }
    __syncthreads();

#pragma unroll
    for (int tx = 0; tx < 3; ++tx) {
      const unsigned short* wtap = W2 + (size_t)(ty * 3 + tx) * 32 * 192;
      // batched af fragments (static indices; proven mfma_tap pattern)
      s16x8 af0[6], af1[6];
#pragma unroll
      for (int s = 0; s < 6; ++s) {
        af0[s] = *(const s16x8*)(wtap + l15 * 192 + s * 32 + hi8);
        af1[s] = *(const s16x8*)(wtap + (16 + l15) * 192 + s * 32 + hi8);
      }
      __builtin_amdgcn_s_setprio(1);
#pragma unroll
      for (int s = 0; s < 6; ++s) {
        int g2a = s * 8 + (lane >> 4) * 2;
        const char* base = LB + g2a * 1040;
#pragma unroll
        for (int nt = 0; nt < 2; ++nt) {
          int j = g * 32 + nt * 16 + l15 + tx;
          u32x2 lo = *(const u32x2u*)(base + j * 8);
          u32x2 hi2 = *(const u32x2u*)(base + 1040 + j * 8);
          u32x4 comb;
          comb[0] = lo.x; comb[1] = lo.y; comb[2] = hi2.x; comb[3] = hi2.y;
          s16x8 bf = __builtin_bit_cast(s16x8, comb);
          if (nt == 0) {
            acc00 = __builtin_amdgcn_mfma_f32_16x16x32_bf16(af0[s], bf, acc00, 0, 0, 0);
            acc10 = __builtin_amdgcn_mfma_f32_16x16x32_bf16(af1[s], bf, acc10, 0, 0, 0);
          } else {
            acc01 = __builtin_amdgcn_mfma_f32_16x16x32_bf16(af0[s], bf, acc01, 0, 0, 0);
            acc11 = __builtin_amdgcn_mfma_f32_16x16x32_bf16(af1[s], bf, acc11, 0, 0, 0);
          }
        }
      }
      __builtin_amdgcn_s_setprio(0);
    }
  }

  // epilogue: rows 0..17 -> off, rows 18..26 -> sigmoid -> mag
#pragma unroll
  for (int mt = 0; mt < 2; ++mt) {
#pragma unroll
    for (int nt = 0; nt < 2; ++nt) {
      f32x4 a = (mt == 0) ? (nt == 0 ? acc00 : acc01)
                          : (nt == 0 ? acc10 : acc11);
      int p = h * WD + g * 32 + nt * 16 + l15;
#pragma unroll
      for (int r = 0; r < 4; ++r) {
        int row = mt * 16 + (lane >> 4) * 4 + r;
        float v = a[r];
        if (row < 18) off_o[((size_t)(b * 18 + row)) * HW + p] = v;
        else if (row < 27) mag_o[((size_t)(b * 9 + row - 18)) * HW + p] = 1.f / (1.f + expf(-v));
      }
    }
  }
}

// ---------------------------------------------------------------------------
// Phase B: deformable sampling + complex contraction (proven ~90µs kernel).
// ---------------------------------------------------------------------------
__global__ __launch_bounds__(256, 4) void k_main_x4(
    const unsigned int* __restrict__ X4,
    const float* __restrict__ off_i, const float* __restrict__ mag_i,
    const unsigned short* __restrict__ Wc,
    const float* __restrict__ b_real, const float* __restrict__ b_imag,
    float* __restrict__ out) {
  __shared__ __align__(16) char LB[2 * 16384];   // 32 KB

  int blk = blockIdx.x;
  int b = blk & 7;                 // XCD-affine
  int rest = blk >> 3;
  int wt = rest & 1;
  int h = rest >> 1;
  int w0 = wt * 64;

  int tid = threadIdx.x;
  int lane = tid & 63;
  int g = tid >> 6;
  int w = w0 + lane;
  int l15 = lane & 15;
  int hi8 = (lane >> 4) * 8;
  int xo = l15 << 4;
  int swz = (lane & 15) << 4;
  int cbase = g * 32;
  const unsigned int* xq = X4 + (size_t)(b * 32 + g * 8) * (2 * HW);
  int ppos = h * WD + w;
  char* sb0 = LB + lane * 256;
  char* sb1 = LB + 16384 + lane * 256;

  f32x4 accR[4], accI[4];
#pragma unroll
  for (int t = 0; t < 4; ++t) {
    accR[t] = (f32x4)(0.f);
    accI[t] = (f32x4)(0.f);
  }

#pragma unroll 1
  for (int ph = 0; ph < 5; ++ph) {
    int kA = ph * 2;
    int kB = kA + 1;
    bool two = (ph < 4);

    float dyA = off_i[((size_t)(b * 18 + 2 * kA)) * HW + ppos];
    float dxA = off_i[((size_t)(b * 18 + 2 * kA + 1)) * HW + ppos];
    float mA  = mag_i[((size_t)(b * 9 + kA)) * HW + ppos];
    float dyB = 0.f, dxB = 0.f, mB = 0.f;
    if (two) {
      dyB = off_i[((size_t)(b * 18 + 2 * kB)) * HW + ppos];
      dxB = off_i[((size_t)(b * 18 + 2 * kB + 1)) * HW + ppos];
      mB  = mag_i[((size_t)(b * 9 + kB)) * HW + ppos];
    }

    __syncthreads();   // prev MFMA phase done reading tap buffers

    {
      float W00, W01, W10, W11; int o0, o1;
      tap_weights(h, w, kA, dyA, dxA, mA, W00, W01, W10, W11, o0, o1);
      gather_tap4(xq, sb0, swz, cbase * 2, W00, W01, W10, W11, o0, o1);
    }
    if (two) {
      float W00, W01, W10, W11; int o0, o1;
      tap_weights(h, w, kB, dyB, dxB, mB, W00, W01, W10, W11, o0, o1);
      gather_tap4(xq, sb1, swz, cbase * 2, W00, W01, W10, W11, o0, o1);
    }
    __syncthreads();

    mfma_tap(Wc, kA, LB, g, l15, hi8, xo, accR, accI);
    if (two)
      mfma_tap(Wc, kB, LB + 16384, g, l15, hi8, xo, accR, accI);
  }

  // epilogue: bias + coalesced nontemporal f32x2 stores
  f32x2* outp = (f32x2*)out;
#pragma unroll
  for (int r = 0; r < 4; ++r) {
    int o = g * 16 + (lane >> 4) * 4 + r;
    float br = b_real[o] - b_imag[o];
#pragma unroll
    for (int t = 0; t < 4; ++t) {
      int pe = h * WD + w0 + t * 16 + l15;
      f32x2 v;
      v.x = accR[t][r] + br;
      v.y = accI[t][r] - br;
      __builtin_nontemporal_store(v, &outp[((size_t)(b * 64 + o)) * HW + pe]);
    }
  }
}

// ---------------------------------------------------------------------------
// Fallback path (ws too small for X4): f32 kernels (round-11 proven).
// ---------------------------------------------------------------------------
__global__ __launch_bounds__(256) void k_offmag_f32(
    const float* __restrict__ xr, const float* __restrict__ xi,
    const unsigned short* __restrict__ W2,
    float* __restrict__ off_o, float* __restrict__ mag_o) {
  __shared__ unsigned short S[66 * 256];
  int blk = blockIdx.x;
  int b = blk & 7;
  int rest = blk >> 3;
  int wt = rest & 1;
  int h = rest >> 1;
  int w0 = wt * 64;
  int tid = threadIdx.x;
  int lane = tid & 63;
  int g = tid >> 6;
  int l15 = lane & 15;
  int hi8 = (lane >> 4) * 8;
  const float* xrb = xr + (size_t)b * 64 * HW;
  const float* xib = xi + (size_t)b * 64 * HW;
  int sub = tid & 3;
  int colm = tid >> 2;
  int jm = colm + 1;
  int wm = w0 + colm;
  f32x4 acc[2];
  acc[0] = (f32x4)(0.f);
  acc[1] = (f32x4)(0.f);
#pragma unroll 1
  for (int ty = 0; ty < 3; ++ty) {
    int y = h + ty - 1;
    if ((unsigned)y >= (unsigned)HD) continue;
    __syncthreads();
    int rb = y * WD;
#pragma unroll
    for (int i = 0; i < 24; ++i) {
      int s = sub + i * 4;
      float v0, v1;
      if (s < 32) {
        const float* p = xrb + (size_t)(2 * s) * HW + rb + wm;
        v0 = p[0]; v1 = p[HW];
      } else if (s < 64) {
        const float* p = xib + (size_t)(2 * s - 64) * HW + rb + wm;
        v0 = p[0]; v1 = p[HW];
      } else {
        int c = 2 * s - 128;
        const float* pr = xrb + (size_t)c * HW + rb + wm;
        const float* pi = xib + (size_t)c * HW + rb + wm;
        float a0 = pr[0], a1 = pr[HW];
        float b0 = pi[0], b1 = pi[HW];
        v0 = sqrtf(a0 * a0 + b0 * b0);
        v1 = sqrtf(a1 * a1 + b1 * b1);
      }
      *(unsigned int*)((char*)S + jm * 512 + ((4 * s) ^ ((jm & 7) << 4))) = pkbf(v0, v1);
    }
    if (tid < 192) {
      int j = (tid < 96) ? 0 : 65;
      int s = (tid < 96) ? tid : tid - 96;
      int wg = (j == 0) ? (w0 - 1) : (w0 + 64);
      float v0 = 0.f, v1 = 0.f;
      if ((unsigned)wg < (unsigned)WD) {
        if (s < 32) {
          const float* p = xrb + (size_t)(2 * s) * HW + rb + wg;
          v0 = p[0]; v1 = p[HW];
        } else if (s < 64) {
          const float* p = xib + (size_t)(2 * s - 64) * HW + rb + wg;
          v0 = p[0]; v1 = p[HW];
        } else {
          int c = 2 * s - 128;
          const float* pr = xrb + (size_t)c * HW + rb + wg;
          const float* pi = xib + (size_t)c * HW + rb + wg;
          float a0 = pr[0], a1 = pr[HW];
          float b0 = pi[0], b1 = pi[HW];
          v0 = sqrtf(a0 * a0 + b0 * b0);
          v1 = sqrtf(a1 * a1 + b1 * b1);
        }
      }
      *(unsigned int*)((char*)S + j * 512 + ((4 * s) ^ ((j & 7) << 4))) = pkbf(v0, v1);
    }
    __syncthreads();
#pragma unroll
    for (int tx = 0; tx < 3; ++tx) {
      const unsigned short* wtap = W2 + (size_t)(ty * 3 + tx) * 32 * 192;
      int j = g * 16 + l15 + tx;
      const char* bcol = (const char*)S + j * 512;
      int xo = (j & 7) << 4;
#pragma unroll
      for (int s = 0; s < 6; ++s) {
        s16x8 bf = *(const s16x8*)(bcol + ((s * 64 + hi8 * 2) ^ xo));
#pragma unroll
        for (int mt = 0; mt < 2; ++mt) {
          s16x8 af = *(const s16x8*)(wtap + (mt * 16 + l15) * 192 + s * 32 + hi8);
          acc[mt] = __builtin_amdgcn_mfma_f32_16x16x32_bf16(af, bf, acc[mt], 0, 0, 0);
        }
      }
    }
  }
  int p = h * WD + w0 + g * 16 + l15;
#pragma unroll
  for (int mt = 0; mt < 2; ++mt) {
#pragma unroll
    for (int r = 0; r < 4; ++r) {
      int row = mt * 16 + (lane >> 4) * 4 + r;
      float v = acc[mt][r];
      if (row < 18) off_o[((size_t)(b * 18 + row)) * HW + p] = v;
      else if (row < 27) mag_o[((size_t)(b * 9 + row - 18)) * HW + p] = 1.f / (1.f + expf(-v));
    }
  }
}

__device__ __forceinline__ void gather_tap_f32(
    const float* xbase, char* sbase, int swz, int cbase2,
    float W00, float W01, float W10, float W11, int o0, int o1) {
#pragma unroll
  for (int q = 0; q < 4; ++q) {
    u32x4 wv;
#pragma unroll
    for (int j2 = 0; j2 < 4; ++j2) {
      const float* p0 = xbase + (size_t)(q * 8 + j2 * 2) * HW;
      const float* p1 = p0 + HW;
      f32x2u a0 = *(const f32x2u*)(p0 + o0);
      f32x2u b0 = *(const f32x2u*)(p0 + o1);
      f32x2u a1 = *(const f32x2u*)(p1 + o0);
      f32x2u b1 = *(const f32x2u*)(p1 + o1);
      float v0 = W00 * a0.x + W01 * a0.y + W10 * b0.x + W11 * b0.y;
      float v1 = W00 * a1.x + W01 * a1.y + W10 * b1.x + W11 * b1.y;
      wv[j2] = pkbf(v0, v1);
    }
    *(u32x4*)(sbase + ((cbase2 + q * 16) ^ swz)) = wv;
  }
}

__global__ __launch_bounds__(256, 4) void k_main_f32(
    const float* __restrict__ xr, const float* __restrict__ xi,
    const float* __restrict__ off_i, const float* __restrict__ mag_i,
    const unsigned short* __restrict__ Wc,
    const float* __restrict__ b_real, const float* __restrict__ b_imag,
    float* __restrict__ out) {
  __shared__ unsigned short S[2 * 64 * 128];
  int blk = blockIdx.x;
  int b = blk & 7;
  int rest = blk >> 3;
  int wt = rest & 1;
  int h = rest >> 1;
  int w0 = wt * 64;
  int tid = threadIdx.x;
  int lane = tid & 63;
  int g = tid >> 6;
  int w = w0 + lane;
  int l15 = lane & 15;
  int hi8 = (lane >> 4) * 8;
  int xo = l15 << 4;
  int swz = (lane & 15) << 4;
  const float* xrb = xr + (size_t)b * 64 * HW;
  const float* xib = xi + (size_t)b * 64 * HW;
  int cbase = g * 32;
  const float* xbase = (g < 2) ? (xrb + (size_t)cbase * HW)
                               : (xib + (size_t)(cbase - 64) * HW);
  int ppos = h * WD + w;
  char* sb0 = (char*)S + lane * 256;
  char* sb1 = (char*)S + 16384 + lane * 256;
  f32x4 accR[4], accI[4];
#pragma unroll
  for (int t = 0; t < 4; ++t) {
    accR[t] = (f32x4)(0.f);
    accI[t] = (f32x4)(0.f);
  }
#pragma unroll 1
  for (int ph = 0; ph < 5; ++ph) {
    int kA = ph * 2;
    int kB = kA + 1;
    bool two = (ph < 4);
    float dyA = off_i[((size_t)(b * 18 + 2 * kA)) * HW + ppos];
    float dxA = off_i[((size_t)(b * 18 + 2 * kA + 1)) * HW + ppos];
    float mA  = mag_i[((size_t)(b * 9 + kA)) * HW + ppos];
    float dyB = 0.f, dxB = 0.f, mB = 0.f;
    if (two) {
      dyB = off_i[((size_t)(b * 18 + 2 * kB)) * HW + ppos];
      dxB = off_i[((size_t)(b * 18 + 2 * kB + 1)) * HW + ppos];
      mB  = mag_i[((size_t)(b * 9 + kB)) * HW + ppos];
    }
    __syncthreads();
    {
      float W00, W01, W10, W11; int o0, o1;
      tap_weights(h, w, kA, dyA, dxA, mA, W00, W01, W10, W11, o0, o1);
      gather_tap_f32(xbase, sb0, swz, cbase * 2, W00, W01, W10, W11, o0, o1);
    }
    if (two) {
      float W00, W01, W10, W11; int o0, o1;
      tap_weights(h, w, kB, dyB, dxB, mB, W00, W01, W10, W11, o0, o1);
      gather_tap_f32(xbase, sb1, swz, cbase * 2, W00, W01, W10, W11, o0, o1);
    }
    __syncthreads();
    mfma_tap(Wc, kA, (const char*)S, g, l15, hi8, xo, accR, accI);
    if (two)
      mfma_tap(Wc, kB, (const char*)S + 16384, g, l15, hi8, xo, accR, accI);
  }
  f32x2* outp = (f32x2*)out;
#pragma unroll
  for (int r = 0; r < 4; ++r) {
    int o = g * 16 + (lane >> 4) * 4 + r;
    float br = b_real[o] - b_imag[o];
#pragma unroll
    for (int t = 0; t < 4; ++t) {
      int pe = h * WD + w0 + t * 16 + l15;
      f32x2 v;
      v.x = accR[t][r] + br;
      v.y = accI[t][r] - br;
      __builtin_nontemporal_store(v, &outp[((size_t)(b * 64 + o)) * HW + pe]);
    }
  }
}

// ---------------------------------------------------------------------------
extern "C" void kernel_launch(void* const* d_in, const int* in_sizes, int n_in,
                              void* d_out, int out_size, void* d_ws, size_t ws_size,
                              hipStream_t stream) {
  const float* xr     = (const float*)d_in[0];
  const float* xi     = (const float*)d_in[1];
  const float* w_off  = (const float*)d_in[2];
  const float* w_mag  = (const float*)d_in[3];
  const float* w_real = (const float*)d_in[4];
  const float* w_imag = (const float*)d_in[5];
  const float* b_real = (const float*)d_in[6];
  const float* b_imag = (const float*)d_in[7];
  float* out = (float*)d_out;

  unsigned short* Wc = (unsigned short*)d_ws;        // 147456 bf16
  unsigned short* W2 = Wc + 147456;                  // 55296 bf16
  float* off_ws = (float*)(W2 + 55296);              // 2359296 f
  float* mag_ws = off_ws + 2359296;                  // 1179648 f
  unsigned int* X4 = (unsigned int*)(mag_ws + 1179648); // 8388608 u32
  const size_t need = ((char*)(X4 + 8388608)) - ((char*)d_ws);
  bool use_x4 = ws_size >= need;

  hipLaunchKernelGGL(k_prepw, dim3(576), dim3(256), 0, stream,
                     w_real, w_imag, Wc);
  hipLaunchKernelGGL(k_prepw2, dim3(216), dim3(256), 0, stream,
                     w_off, w_mag, W2);
  if (use_x4) {
    hipLaunchKernelGGL(k_prepx4, dim3(4096), dim3(256), 0, stream, xr, xi, X4);
    hipLaunchKernelGGL(k_offmag_x4, dim3(1024), dim3(256), 0, stream,
                       X4, W2, off_ws, mag_ws);
    hipLaunchKernelGGL(k_main_x4, dim3(2048), dim3(256), 0, stream,
                       X4, off_ws, mag_ws, Wc, b_real, b_imag, out);
  } else {
    hipLaunchKernelGGL(k_offmag_f32, dim3(2048), dim3(256), 0, stream,
                       xr, xi, W2, off_ws, mag_ws);
    hipLaunchKernelGGL(k_main_f32, dim3(2048), dim3(256), 0, stream,
                       xr, xi, off_ws, mag_ws, Wc, b_real, b_imag, out);
  }
}